// Round 16
// baseline (185.079 us; speedup 1.0000x reference)
//
#include <hip/hip_runtime.h>
#include <math.h>

#define NB 512
#define LONGN 1000
#define SHORTN 50
#define TOPKN 50
#define HALFN 500
#define NG 8          // item-groups per hard block
#define EROW 72       // hard-path bf16 LDS row stride (shorts)
#define BROW 72       // bst bf16 row stride (shorts) for xbf/obf
#define F1ROW 136     // bst bf16 row stride for ff1 output (128+8)

typedef __attribute__((ext_vector_type(8))) short bf16x8;
typedef __attribute__((ext_vector_type(4))) float f32x4;

__device__ __forceinline__ float dot4(float4 a, float4 b) {
  return a.x*b.x + a.y*b.y + a.z*b.z + a.w*b.w;
}

template<int N>
__device__ __forceinline__ float dotN(const float* w, const float* x) {
  const float4* w4 = (const float4*)w;
  const float4* x4 = (const float4*)x;
  float a0 = 0.f, a1 = 0.f, a2 = 0.f, a3 = 0.f;
  #pragma unroll
  for (int k = 0; k < N/4; k += 4) {
    a0 += dot4(w4[k],   x4[k]);
    a1 += dot4(w4[k+1], x4[k+1]);
    a2 += dot4(w4[k+2], x4[k+2]);
    a3 += dot4(w4[k+3], x4[k+3]);
  }
  return (a0 + a1) + (a2 + a3);
}

__device__ __forceinline__ float wave_sum(float v) {
  #pragma unroll
  for (int off = 32; off > 0; off >>= 1) v += __shfl_xor(v, off);
  return v;
}
__device__ __forceinline__ float wave_max(float v) {
  #pragma unroll
  for (int off = 32; off > 0; off >>= 1) v = fmaxf(v, __shfl_xor(v, off));
  return v;
}

__device__ __forceinline__ unsigned short f2bf(float x) {  // RNE fp32->bf16
  unsigned u = __float_as_uint(x);
  return (unsigned short)((u + 0x7fffu + ((u >> 16) & 1u)) >> 16);
}

// ===========================================================================
// K1 (MFMA): hard-search scores. v2: 2-deep register prefetch (two named
// float4 sets, fully unrolled schedule -> 2 gather-sets in flight per wave);
// bst weight prep folded into blocks 0..31 (saves a launch).
// ===========================================================================
__global__ __launch_bounds__(256, 3) void hard_scores_kernel(
    const int* __restrict__ target_item_id,
    const int* __restrict__ long_hist_ids,
    const float* __restrict__ item_emb,
    const float* __restrict__ tproj_w, const float* __restrict__ tproj_b,
    const float* __restrict__ attn_w1, const float* __restrict__ attn_b1,
    const float* __restrict__ attn_w2, const float* __restrict__ attn_b2,
    const float* __restrict__ hash_emb,
    const float* __restrict__ qkv_w, const float* __restrict__ out_w,
    const float* __restrict__ ff1_w, const float* __restrict__ ff2_w,
    short* __restrict__ wF,
    float* __restrict__ scores_ws, float* __restrict__ partA,
    float* __restrict__ partH)
{
  __shared__ __align__(16) short Abf[64*EROW];
  __shared__ __align__(16) short Ebuf[2][64*EROW];
  __shared__ __align__(16) float tv[64];
  __shared__ __align__(16) float te[64];
  __shared__ __align__(16) float2 cw[64];
  __shared__ int idsL[HALFN];
  __shared__ __align__(16) float redE[4*64];

  const int bid = blockIdx.x;
  const int b = bid >> 1, half = bid & 1;
  const int base = half * HALFN;
  const int tid = threadIdx.x;
  const int wid = tid >> 6, lane = tid & 63;

  // ---- folded bst weight prep (blocks 0..31; wF ready before bst launch) ----
  if (bid < 32) {
    const int t = bid*256 + tid;
    const int fid = t >> 6, plane = t & 63;
    const int n16p = plane & 15, k8 = (plane >> 4) * 8;
    const float* src;
    if (fid < 48)      { int f=fid,    l=f/24, r=f%24, nt=r>>1, kc=r&1;
      src = qkv_w + l*12288 + (nt*16+n16p)*64 + kc*32 + k8; }
    else if (fid < 64) { int f=fid-48, l=f>>3, r=f&7,  nt=r>>1, kc=r&1;
      src = out_w + l*4096 + (nt*16+n16p)*64 + kc*32 + k8; }
    else if (fid < 96) { int f=fid-64, l=f>>4, r=f&15, nt=r>>1, kc=r&1;
      src = ff1_w + l*8192 + (nt*16+n16p)*64 + kc*32 + k8; }
    else               { int f=fid-96, l=f>>4, r=f&15, nt=r>>2, kc=r&3;
      src = ff2_w + l*8192 + (nt*16+n16p)*128 + kc*32 + k8; }
    short* dst = wF + fid*512 + plane*8;
    #pragma unroll
    for (int j = 0; j < 8; ++j) dst[j] = (short)f2bf(src[j]);
  }

  if (tid < 64) tv[tid] = item_emb[target_item_id[b]*64 + tid];
  for (int l = tid; l < HALFN; l += 256) idsL[l] = long_hist_ids[b*LONGN + base + l];
  __syncthreads();
  if (tid < 64) te[tid] = tproj_b[tid] + dotN<64>(tproj_w + tid*64, tv);
  __syncthreads();
  if (tid < 64) {
    float c = attn_b1[tid] + dotN<64>(attn_w1 + tid*192, te);
    cw[tid] = make_float2(c, attn_w2[tid]);
  }
  for (int idx = tid; idx < 4096; idx += 256) {
    int i = idx >> 6, j = idx & 63;
    Abf[i*EROW + j] = (short)f2bf(attn_w1[i*192 + 64 + j] + attn_w1[i*192 + 128 + j]*te[j]);
  }
  __syncthreads();

  bf16x8 a00,a01,a10,a11,a20,a21,a30,a31;
  {
    const short* ap = Abf + (lane & 15)*EROW + ((lane >> 4) << 3);
    a00 = *(const bf16x8*)(ap +  0*EROW);  a01 = *(const bf16x8*)(ap +  0*EROW + 32);
    a10 = *(const bf16x8*)(ap + 16*EROW);  a11 = *(const bf16x8*)(ap + 16*EROW + 32);
    a20 = *(const bf16x8*)(ap + 32*EROW);  a21 = *(const bf16x8*)(ap + 32*EROW + 32);
    a30 = *(const bf16x8*)(ap + 48*EROW);  a31 = *(const bf16x8*)(ap + 48*EROW + 32);
  }

  const float b2s = attn_b2[0];
  const int it_g = tid >> 2;
  const int dimg = (tid & 3) * 16;

  float4 sE0 = {0,0,0,0}, sE1 = {0,0,0,0}, sE2 = {0,0,0,0}, sE3 = {0,0,0,0};
  float4 pA0, pA1, pA2, pA3;   // even groups
  float4 pB0, pB1, pB2, pB3;   // odd groups

#define LOADG(G, R0, R1, R2, R3)                                              \
  {                                                                           \
    R0 = make_float4(0,0,0,0); R1 = R0; R2 = R0; R3 = R0;                     \
    const int gi_ = (G)*64 + it_g;                                            \
    if (gi_ < HALFN) {                                                        \
      const float4* ep_ = (const float4*)(item_emb + (size_t)idsL[gi_]*64 + dimg); \
      R0 = ep_[0]; R1 = ep_[1]; R2 = ep_[2]; R3 = ep_[3];                     \
    }                                                                         \
  }

#define STOREG(DST, R0, R1, R2, R3)                                           \
  {                                                                           \
    sE0.x+=R0.x; sE0.y+=R0.y; sE0.z+=R0.z; sE0.w+=R0.w;                       \
    sE1.x+=R1.x; sE1.y+=R1.y; sE1.z+=R1.z; sE1.w+=R1.w;                       \
    sE2.x+=R2.x; sE2.y+=R2.y; sE2.z+=R2.z; sE2.w+=R2.w;                       \
    sE3.x+=R3.x; sE3.y+=R3.y; sE3.z+=R3.z; sE3.w+=R3.w;                       \
    bf16x8 w0_, w1_;                                                          \
    w0_[0]=(short)f2bf(R0.x); w0_[1]=(short)f2bf(R0.y);                       \
    w0_[2]=(short)f2bf(R0.z); w0_[3]=(short)f2bf(R0.w);                       \
    w0_[4]=(short)f2bf(R1.x); w0_[5]=(short)f2bf(R1.y);                       \
    w0_[6]=(short)f2bf(R1.z); w0_[7]=(short)f2bf(R1.w);                       \
    w1_[0]=(short)f2bf(R2.x); w1_[1]=(short)f2bf(R2.y);                       \
    w1_[2]=(short)f2bf(R2.z); w1_[3]=(short)f2bf(R2.w);                       \
    w1_[4]=(short)f2bf(R3.x); w1_[5]=(short)f2bf(R3.y);                       \
    w1_[6]=(short)f2bf(R3.z); w1_[7]=(short)f2bf(R3.w);                       \
    short* dst_ = &Ebuf[DST][it_g*EROW + dimg];                               \
    *(bf16x8*)dst_ = w0_;  *(bf16x8*)(dst_ + 8) = w1_;                        \
  }

#define COMPUTEG(BUF, G)                                                      \
  {                                                                           \
    f32x4 acc0={0,0,0,0}, acc1={0,0,0,0}, acc2={0,0,0,0}, acc3={0,0,0,0};     \
    const short* ep_ = &Ebuf[BUF][(wid*16 + (lane & 15))*EROW + ((lane >> 4) << 3)]; \
    bf16x8 b0_ = *(const bf16x8*)(ep_);                                       \
    bf16x8 b1_ = *(const bf16x8*)(ep_ + 32);                                  \
    acc0 = __builtin_amdgcn_mfma_f32_16x16x32_bf16(a00, b0_, acc0, 0,0,0);    \
    acc0 = __builtin_amdgcn_mfma_f32_16x16x32_bf16(a01, b1_, acc0, 0,0,0);    \
    acc1 = __builtin_amdgcn_mfma_f32_16x16x32_bf16(a10, b0_, acc1, 0,0,0);    \
    acc1 = __builtin_amdgcn_mfma_f32_16x16x32_bf16(a11, b1_, acc1, 0,0,0);    \
    acc2 = __builtin_amdgcn_mfma_f32_16x16x32_bf16(a20, b0_, acc2, 0,0,0);    \
    acc2 = __builtin_amdgcn_mfma_f32_16x16x32_bf16(a21, b1_, acc2, 0,0,0);    \
    acc3 = __builtin_amdgcn_mfma_f32_16x16x32_bf16(a30, b0_, acc3, 0,0,0);    \
    acc3 = __builtin_amdgcn_mfma_f32_16x16x32_bf16(a31, b1_, acc3, 0,0,0);    \
    float p_ = 0.f;                                                           \
    const int rbase_ = (lane >> 4) << 2;                                      \
    _Pragma("unroll")                                                         \
    for (int r = 0; r < 4; ++r) {                                             \
      float2 c0_ = cw[ 0 + rbase_ + r];                                       \
      float2 c1_ = cw[16 + rbase_ + r];                                       \
      float2 c2_ = cw[32 + rbase_ + r];                                       \
      float2 c3_ = cw[48 + rbase_ + r];                                       \
      p_ += c0_.y * fmaxf(acc0[r] + c0_.x, 0.f);                              \
      p_ += c1_.y * fmaxf(acc1[r] + c1_.x, 0.f);                              \
      p_ += c2_.y * fmaxf(acc2[r] + c2_.x, 0.f);                              \
      p_ += c3_.y * fmaxf(acc3[r] + c3_.x, 0.f);                              \
    }                                                                         \
    p_ += __shfl_xor(p_, 16);                                                 \
    p_ += __shfl_xor(p_, 32);                                                 \
    if (lane < 16) {                                                          \
      const int gi_ = (G)*64 + wid*16 + lane;                                 \
      if (gi_ < HALFN) scores_ws[b*LONGN + base + gi_] = b2s + p_;            \
    }                                                                         \
  }

  // ---- prologue: groups 0,1 in regs; stage group 0 ----
  LOADG(0, pA0, pA1, pA2, pA3);
  LOADG(1, pB0, pB1, pB2, pB3);
  STOREG(0, pA0, pA1, pA2, pA3);
  __syncthreads();

  // ---- 2-deep pipelined schedule (group g staged in Ebuf[g&1]) ----
  LOADG(2, pA0, pA1, pA2, pA3);  COMPUTEG(0, 0);  STOREG(1, pB0, pB1, pB2, pB3);  __syncthreads();
  LOADG(3, pB0, pB1, pB2, pB3);  COMPUTEG(1, 1);  STOREG(0, pA0, pA1, pA2, pA3);  __syncthreads();
  LOADG(4, pA0, pA1, pA2, pA3);  COMPUTEG(0, 2);  STOREG(1, pB0, pB1, pB2, pB3);  __syncthreads();
  LOADG(5, pB0, pB1, pB2, pB3);  COMPUTEG(1, 3);  STOREG(0, pA0, pA1, pA2, pA3);  __syncthreads();
  LOADG(6, pA0, pA1, pA2, pA3);  COMPUTEG(0, 4);  STOREG(1, pB0, pB1, pB2, pB3);  __syncthreads();
  LOADG(7, pB0, pB1, pB2, pB3);  COMPUTEG(1, 5);  STOREG(0, pA0, pA1, pA2, pA3);  __syncthreads();
                                 COMPUTEG(0, 6);  STOREG(1, pB0, pB1, pB2, pB3);  __syncthreads();
                                 COMPUTEG(1, 7);

#undef LOADG
#undef STOREG
#undef COMPUTEG

  // ---- mean-emb reduction (sums accumulated during staging) ----
  {
    float* red = (float*)&Ebuf[0][0];
    const int b17 = tid * 17;
    red[b17+ 0]=sE0.x; red[b17+ 1]=sE0.y; red[b17+ 2]=sE0.z; red[b17+ 3]=sE0.w;
    red[b17+ 4]=sE1.x; red[b17+ 5]=sE1.y; red[b17+ 6]=sE1.z; red[b17+ 7]=sE1.w;
    red[b17+ 8]=sE2.x; red[b17+ 9]=sE2.y; red[b17+10]=sE2.z; red[b17+11]=sE2.w;
    red[b17+12]=sE3.x; red[b17+13]=sE3.y; red[b17+14]=sE3.z; red[b17+15]=sE3.w;
    __syncthreads();
    if (tid < 64) {
      const int dg = tid >> 4, dw = tid & 15;
      float s = 0.f;
      for (int j = 0; j < 64; ++j) s += red[(j*4 + dg)*17 + dw];
      partA[bid*64 + tid] = s;
    }
  }

  {
    const int hl = lane >> 4, dd = lane & 15;
    const float* hb = hash_emb + hl*1024*16 + dd;
    float accH = 0.f;
    for (int l = wid; l < HALFN; l += 4)
      accH += hb[(idsL[l] & 1023)*16];
    redE[wid*64 + lane] = accH;
  }
  __syncthreads();
  if (wid == 0)
    partH[bid*64 + lane] = redE[lane] + redE[64+lane] + redE[128+lane] + redE[192+lane];
}

// ===========================================================================
// BST transformer v10 (unchanged from R15): 512 threads, M-split waves,
// 400-thread K-split attention.
// ===========================================================================
__global__ __launch_bounds__(512, 2) void bst_kernel(
    const int* __restrict__ short_ids, const float* __restrict__ item_emb,
    const short* __restrict__ wF,
    const float* __restrict__ qkv_b, const float* __restrict__ out_b,
    const float* __restrict__ ln1_g, const float* __restrict__ ln1_b,
    const float* __restrict__ ff1_b, const float* __restrict__ ff2_b,
    const float* __restrict__ ln2_g, const float* __restrict__ ln2_b,
    float* __restrict__ bst_out)
{
  __shared__ __align__(16) float xf[SHORTN*64];
  __shared__ __align__(16) short xbf[64*BROW];
  __shared__ __align__(16) float qf[SHORTN*68];
  __shared__ __align__(16) float arena[SHORTN*132];
  __shared__ __align__(16) short obf[64*BROW];

  short* f1bf = (short*)arena;

  const int b = blockIdx.x, tid = threadIdx.x;
  const int w8 = tid >> 6, lane = tid & 63;
  const int mh = w8 & 1, wg = w8 >> 1;
  const int n16 = lane & 15;
  const int kg8 = (lane >> 4) << 3;
  const int mrow = (lane >> 4) << 2;
  const int rb = 32*mh;

  for (int idx = tid; idx < SHORTN*64; idx += 512) {
    int s = idx >> 6, j = idx & 63;
    float v = item_emb[short_ids[b*SHORTN + s]*64 + j];
    xf[idx] = v;
    xbf[s*BROW + j] = (short)f2bf(v);
  }
  for (int idx = tid; idx < 14*BROW; idx += 512) {
    xbf[50*BROW + idx] = 0;
    obf[50*BROW + idx] = 0;
  }
  __syncthreads();

  for (int l = 0; l < 2; ++l) {
    // ======== qkv ========
    {
      const short* ap = xbf + (rb + n16)*BROW + kg8;
      bf16x8 A00 = *(const bf16x8*)(ap);            bf16x8 A01 = *(const bf16x8*)(ap + 32);
      bf16x8 A10 = *(const bf16x8*)(ap + 16*BROW);  bf16x8 A11 = *(const bf16x8*)(ap + 16*BROW + 32);
      #pragma unroll
      for (int t = 0; t < 3; ++t) {
        const int nt = wg*3 + t;
        const short* bp = wF + (size_t)(l*24 + nt*2)*512 + lane*8;
        bf16x8 B0 = *(const bf16x8*)(bp);
        bf16x8 B1 = *(const bf16x8*)(bp + 512);
        f32x4 c0={0,0,0,0}, c1={0,0,0,0};
        c0 = __builtin_amdgcn_mfma_f32_16x16x32_bf16(A00, B0, c0, 0,0,0);
        c0 = __builtin_amdgcn_mfma_f32_16x16x32_bf16(A01, B1, c0, 0,0,0);
        c1 = __builtin_amdgcn_mfma_f32_16x16x32_bf16(A10, B0, c1, 0,0,0);
        c1 = __builtin_amdgcn_mfma_f32_16x16x32_bf16(A11, B1, c1, 0,0,0);
        const int c = nt*16 + n16;
        const float bias = qkv_b[l*192 + c];
        #pragma unroll
        for (int r = 0; r < 4; ++r) {
          const int r0 = rb + mrow + r;
          const int r1 = r0 + 16;
          float v0 = c0[r] + bias;
          float v1 = c1[r] + bias;
          if (c < 64) {
            qf[r0*68 + c] = v0;
            if (r1 < SHORTN) qf[r1*68 + c] = v1;
          } else {
            const int cc = c - 64;
            arena[r0*132 + cc] = v0;
            if (r1 < SHORTN) arena[r1*132 + cc] = v1;
          }
        }
      }
    }
    __syncthreads();

    // ======== attention: 400 threads, pair-split K ========
    if (tid < 8*SHORTN) {
      const int pair = tid >> 1, khalf = tid & 1;
      const int h = pair / SHORTN, s = pair - h*SHORTN;
      const float4* qp = (const float4*)(qf + s*68 + h*16);
      const float4 qA = qp[0], qB2 = qp[1], qC = qp[2], qD = qp[3];
      float ss = 0.f;
      float4 oa0 = {0,0,0,0}, oa1 = {0,0,0,0}, oa2 = {0,0,0,0}, oa3 = {0,0,0,0};
      const int t0 = khalf*25;
      for (int t2 = t0; t2 < t0 + 25; ++t2) {
        const float4* kp = (const float4*)(arena + t2*132 + h*16);
        float d = dot4(qA,kp[0]) + dot4(qB2,kp[1]) + dot4(qC,kp[2]) + dot4(qD,kp[3]);
        float p = __expf(d*0.25f);
        ss += p;
        const float4* vp = (const float4*)(arena + t2*132 + 64 + h*16);
        float4 v0 = vp[0], v1 = vp[1], v2 = vp[2], v3 = vp[3];
        oa0.x += p*v0.x; oa0.y += p*v0.y; oa0.z += p*v0.z; oa0.w += p*v0.w;
        oa1.x += p*v1.x; oa1.y += p*v1.y; oa1.z += p*v1.z; oa1.w += p*v1.w;
        oa2.x += p*v2.x; oa2.y += p*v2.y; oa2.z += p*v2.z; oa2.w += p*v2.w;
        oa3.x += p*v3.x; oa3.y += p*v3.y; oa3.z += p*v3.z; oa3.w += p*v3.w;
      }
      ss    += __shfl_xor(ss, 1);
      oa0.x += __shfl_xor(oa0.x, 1); oa0.y += __shfl_xor(oa0.y, 1);
      oa0.z += __shfl_xor(oa0.z, 1); oa0.w += __shfl_xor(oa0.w, 1);
      oa1.x += __shfl_xor(oa1.x, 1); oa1.y += __shfl_xor(oa1.y, 1);
      oa1.z += __shfl_xor(oa1.z, 1); oa1.w += __shfl_xor(oa1.w, 1);
      oa2.x += __shfl_xor(oa2.x, 1); oa2.y += __shfl_xor(oa2.y, 1);
      oa2.z += __shfl_xor(oa2.z, 1); oa2.w += __shfl_xor(oa2.w, 1);
      oa3.x += __shfl_xor(oa3.x, 1); oa3.y += __shfl_xor(oa3.y, 1);
      oa3.z += __shfl_xor(oa3.z, 1); oa3.w += __shfl_xor(oa3.w, 1);
      if (khalf == 0) {
        const float inv = 1.f/ss;
        bf16x8 w0, w1;
        w0[0]=(short)f2bf(oa0.x*inv); w0[1]=(short)f2bf(oa0.y*inv);
        w0[2]=(short)f2bf(oa0.z*inv); w0[3]=(short)f2bf(oa0.w*inv);
        w0[4]=(short)f2bf(oa1.x*inv); w0[5]=(short)f2bf(oa1.y*inv);
        w0[6]=(short)f2bf(oa1.z*inv); w0[7]=(short)f2bf(oa1.w*inv);
        w1[0]=(short)f2bf(oa2.x*inv); w1[1]=(short)f2bf(oa2.y*inv);
        w1[2]=(short)f2bf(oa2.z*inv); w1[3]=(short)f2bf(oa2.w*inv);
        w1[4]=(short)f2bf(oa3.x*inv); w1[5]=(short)f2bf(oa3.y*inv);
        w1[6]=(short)f2bf(oa3.z*inv); w1[7]=(short)f2bf(oa3.w*inv);
        short* op = obf + s*BROW + h*16;
        *(bf16x8*)op = w0;  *(bf16x8*)(op + 8) = w1;
      }
    }
    __syncthreads();

    // ======== out-proj + y ========
    {
      const short* ap = obf + (rb + n16)*BROW + kg8;
      bf16x8 A00 = *(const bf16x8*)(ap);            bf16x8 A01 = *(const bf16x8*)(ap + 32);
      bf16x8 A10 = *(const bf16x8*)(ap + 16*BROW);  bf16x8 A11 = *(const bf16x8*)(ap + 16*BROW + 32);
      const int nt = wg;
      const short* bp = wF + (size_t)(48 + l*8 + nt*2)*512 + lane*8;
      bf16x8 B0 = *(const bf16x8*)(bp);
      bf16x8 B1 = *(const bf16x8*)(bp + 512);
      f32x4 c0={0,0,0,0}, c1={0,0,0,0};
      c0 = __builtin_amdgcn_mfma_f32_16x16x32_bf16(A00, B0, c0, 0,0,0);
      c0 = __builtin_amdgcn_mfma_f32_16x16x32_bf16(A01, B1, c0, 0,0,0);
      c1 = __builtin_amdgcn_mfma_f32_16x16x32_bf16(A10, B0, c1, 0,0,0);
      c1 = __builtin_amdgcn_mfma_f32_16x16x32_bf16(A11, B1, c1, 0,0,0);
      const int c = nt*16 + n16;
      const float bias = out_b[l*64 + c];
      #pragma unroll
      for (int r = 0; r < 4; ++r) {
        const int r0 = rb + mrow + r;
        const int r1 = r0 + 16;
        arena[r0*68 + c] = xf[r0*64 + c] + bias + c0[r];
        if (r1 < SHORTN) arena[r1*68 + c] = xf[r1*64 + c] + bias + c1[r];
      }
      for (int idx = tid; idx < 14*F1ROW; idx += 512) f1bf[50*F1ROW + idx] = 0;
    }
    __syncthreads();

    // ======== LN1 ========
    {
      const float g = ln1_g[l*64 + lane], bb = ln1_b[l*64 + lane];
      for (int s = w8; s < SHORTN; s += 8) {
        float y = arena[s*68 + lane];
        float mean = wave_sum(y) * (1.f/64.f);
        float dv = y - mean;
        float var = wave_sum(dv*dv) * (1.f/64.f);
        float r = dv / sqrtf(var + 1e-5f) * g + bb;
        xf[s*64 + lane] = r;
        xbf[s*BROW + lane] = (short)f2bf(r);
      }
    }
    __syncthreads();

    // ======== ff1 ========
    {
      const short* ap = xbf + (rb + n16)*BROW + kg8;
      bf16x8 A00 = *(const bf16x8*)(ap);            bf16x8 A01 = *(const bf16x8*)(ap + 32);
      bf16x8 A10 = *(const bf16x8*)(ap + 16*BROW);  bf16x8 A11 = *(const bf16x8*)(ap + 16*BROW + 32);
      #pragma unroll
      for (int t = 0; t < 2; ++t) {
        const int nt = wg*2 + t;
        const short* bp = wF + (size_t)(64 + l*16 + nt*2)*512 + lane*8;
        bf16x8 B0 = *(const bf16x8*)(bp);
        bf16x8 B1 = *(const bf16x8*)(bp + 512);
        f32x4 c0={0,0,0,0}, c1={0,0,0,0};
        c0 = __builtin_amdgcn_mfma_f32_16x16x32_bf16(A00, B0, c0, 0,0,0);
        c0 = __builtin_amdgcn_mfma_f32_16x16x32_bf16(A01, B1, c0, 0,0,0);
        c1 = __builtin_amdgcn_mfma_f32_16x16x32_bf16(A10, B0, c1, 0,0,0);
        c1 = __builtin_amdgcn_mfma_f32_16x16x32_bf16(A11, B1, c1, 0,0,0);
        const int c = nt*16 + n16;
        const float bias = ff1_b[l*128 + c];
        #pragma unroll
        for (int r = 0; r < 4; ++r) {
          const int r0 = rb + mrow + r;
          const int r1 = r0 + 16;
          f1bf[r0*F1ROW + c] = (short)f2bf(fmaxf(c0[r] + bias, 0.f));
          if (r1 < SHORTN) f1bf[r1*F1ROW + c] = (short)f2bf(fmaxf(c1[r] + bias, 0.f));
        }
      }
    }
    __syncthreads();

    // ======== ff2 ========
    {
      const int nt = wg;
      f32x4 c0={0,0,0,0}, c1={0,0,0,0};
      #pragma unroll
      for (int kc = 0; kc < 4; ++kc) {
        const short* ap = f1bf + (rb + n16)*F1ROW + kc*32 + kg8;
        bf16x8 A0 = *(const bf16x8*)(ap);
        bf16x8 A1 = *(const bf16x8*)(ap + 16*F1ROW);
        const short* bp = wF + (size_t)(96 + l*16 + nt*4 + kc)*512 + lane*8;
        bf16x8 B = *(const bf16x8*)(bp);
        c0 = __builtin_amdgcn_mfma_f32_16x16x32_bf16(A0, B, c0, 0,0,0);
        c1 = __builtin_amdgcn_mfma_f32_16x16x32_bf16(A1, B, c1, 0,0,0);
      }
      __syncthreads();
      const int c = nt*16 + n16;
      const float bias = ff2_b[l*64 + c];
      #pragma unroll
      for (int r = 0; r < 4; ++r) {
        const int r0 = rb + mrow + r;
        const int r1 = r0 + 16;
        arena[r0*68 + c] = xf[r0*64 + c] + bias + c0[r];
        if (r1 < SHORTN) arena[r1*68 + c] = xf[r1*64 + c] + bias + c1[r];
      }
    }
    __syncthreads();

    // ======== LN2 ========
    {
      const float g = ln2_g[l*64 + lane], bb = ln2_b[l*64 + lane];
      for (int s = w8; s < SHORTN; s += 8) {
        float y = arena[s*68 + lane];
        float mean = wave_sum(y) * (1.f/64.f);
        float dv = y - mean;
        float var = wave_sum(dv*dv) * (1.f/64.f);
        float r = dv / sqrtf(var + 1e-5f) * g + bb;
        xf[s*64 + lane] = r;
        xbf[s*BROW + lane] = (short)f2bf(r);
      }
    }
    __syncthreads();
  }

  float acc = 0.f;
  for (int s = w8; s < SHORTN; s += 8) acc += xf[s*64 + lane];
  qf[w8*64 + lane] = acc;
  __syncthreads();
  if (w8 == 0) {
    float t = qf[lane];
    #pragma unroll
    for (int w = 1; w < 8; ++w) t += qf[w*64 + lane];
    bst_out[b*64 + lane] = t * (1.f/50.f);
  }
}

// ===========================================================================
// K2+K4 merged, 512 threads (unchanged from R15).
// ===========================================================================
__global__ __launch_bounds__(512) void hard_finish_fusion_kernel(
    const int* __restrict__ long_hist_ids,
    const float* __restrict__ item_emb,
    const float* __restrict__ sdim_w, const float* __restrict__ sdim_b,
    const float* __restrict__ scores_ws,
    const float* __restrict__ partA, const float* __restrict__ partH,
    const float* __restrict__ user, const float* __restrict__ bst,
    const float* __restrict__ w1, const float* __restrict__ b1,
    const float* __restrict__ w2, const float* __restrict__ b2,
    const float* __restrict__ w3, const float* __restrict__ b3,
    float* __restrict__ out)
{
  __shared__ __align__(16) float scores[LONGN];
  __shared__ int   idsL[LONGN];
  __shared__ __align__(16) unsigned long long kv[1024];
  __shared__ __align__(16) float redE[8*64];
  __shared__ __align__(16) float vecbuf[64];
  __shared__ float redV[8];
  __shared__ float selV[TOPKN];
  __shared__ int   selI[TOPKN];
  __shared__ __align__(16) float comb[256];
  __shared__ __align__(16) float h1[256];
  __shared__ __align__(16) float h2[128];

  const int b = blockIdx.x;
  const int tid = threadIdx.x;
  const int wid = tid >> 6, lane = tid & 63;

  for (int l = tid; l < LONGN; l += 512) {
    scores[l] = scores_ws[b*LONGN + l];
    idsL[l] = long_hist_ids[b*LONGN + l];
  }
  if (tid < 64)                          comb[tid] = user[b*64 + tid];
  else if (tid >= 192 && tid < 256)      comb[tid] = bst[b*64 + tid - 192];
  __syncthreads();

  if (tid < 64)
    vecbuf[tid] = (partA[(2*b)*64 + tid] + partA[(2*b+1)*64 + tid]
                 + partH[(2*b)*64 + tid] + partH[(2*b+1)*64 + tid]) * (1.f/1000.f);
  __syncthreads();
  if (tid < 64)
    comb[128 + tid] = sdim_b[tid] + dotN<64>(sdim_w + tid*64, vecbuf);

  float mx = -INFINITY;
  for (int l = tid; l < LONGN; l += 512) mx = fmaxf(mx, scores[l]);
  mx = wave_max(mx);
  if (lane == 0) redV[wid] = mx;
  __syncthreads();
  mx = redV[0];
  #pragma unroll
  for (int w = 1; w < 8; ++w) mx = fmaxf(mx, redV[w]);
  __syncthreads();
  float sm = 0.f;
  for (int l = tid; l < LONGN; l += 512) {
    float a = expf(scores[l] - mx);
    scores[l] = a;
    sm += a;
  }
  sm = wave_sum(sm);
  if (lane == 0) redV[wid] = sm;
  __syncthreads();
  {
    float tot = redV[0];
    #pragma unroll
    for (int w = 1; w < 8; ++w) tot += redV[w];
    const float inv = 1.f / tot;
    for (int l = tid; l < LONGN; l += 512) scores[l] *= inv;
  }
  __syncthreads();

  for (int l = tid; l < 1024; l += 512) {
    if (l < LONGN) {
      unsigned vb = __float_as_uint(scores[l]);
      kv[l] = ((unsigned long long)(~vb) << 32) | (unsigned)l;
    } else {
      kv[l] = 0xFFFFFFFFFFFFFFFFull;
    }
  }
  __syncthreads();

  for (int k = 2; k <= 1024; k <<= 1) {
    for (int j = k >> 1; j > 0; j >>= 1) {
      {
        const int p = tid;
        const int i = ((p & ~(j-1)) << 1) | (p & (j-1));
        const int m = i + j;
        const bool up = ((i & k) == 0);
        unsigned long long a = kv[i], c = kv[m];
        if ((a > c) == up) { kv[i] = c; kv[m] = a; }
      }
      __syncthreads();
    }
  }

  if (tid < TOPKN) {
    unsigned long long key = kv[tid];
    selI[tid] = (int)(unsigned)(key & 0xFFFFFFFFu);
    selV[tid] = __uint_as_float(~(unsigned)(key >> 32));
  }
  __syncthreads();

  if (wid == 0) {
    float v = (lane < TOPKN) ? selV[lane] : -INFINITY;
    float m2 = wave_max(v);
    float e = (lane < TOPKN) ? expf(v - m2) : 0.f;
    float s2 = wave_sum(e);
    if (lane < TOPKN) selV[lane] = e / s2;
  }
  __syncthreads();

  float accR = 0.f;
  for (int r = wid; r < TOPKN; r += 8)
    accR += selV[r] * item_emb[idsL[selI[r]]*64 + lane];
  redE[wid*64 + lane] = accR;
  __syncthreads();
  if (wid == 0) {
    float t = redE[lane];
    #pragma unroll
    for (int w = 1; w < 8; ++w) t += redE[w*64 + lane];
    comb[64 + lane] = t;
  }
  __syncthreads();

  if (tid < 256) h1[tid] = fmaxf(b1[tid] + dotN<256>(w1 + tid*256, comb), 0.f);
  __syncthreads();
  if (tid < 128) h2[tid] = fmaxf(b2[tid] + dotN<256>(w2 + tid*256, h1), 0.f);
  __syncthreads();
  if (tid < 64) {
    float p = w3[tid]*h2[tid] + w3[tid+64]*h2[tid+64];
    p = wave_sum(p);
    if (tid == 0) out[b] = p + b3[0];
  }
}

extern "C" void kernel_launch(void* const* d_in, const int* in_sizes, int n_in,
                              void* d_out, int out_size, void* d_ws, size_t ws_size,
                              hipStream_t stream) {
  const float* user_features  = (const float*)d_in[0];
  const int*   target_item_id = (const int*)  d_in[1];
  const int*   short_hist_ids = (const int*)  d_in[2];
  const int*   long_hist_ids  = (const int*)  d_in[3];
  const float* item_emb       = (const float*)d_in[4];
  const float* tproj_w  = (const float*)d_in[5];
  const float* tproj_b  = (const float*)d_in[6];
  const float* attn_w1  = (const float*)d_in[7];
  const float* attn_b1  = (const float*)d_in[8];
  const float* attn_w2  = (const float*)d_in[9];
  const float* attn_b2  = (const float*)d_in[10];
  const float* hash_emb = (const float*)d_in[11];
  const float* sdim_w   = (const float*)d_in[12];
  const float* sdim_b   = (const float*)d_in[13];
  const float* tf_qkv_w = (const float*)d_in[14];
  const float* tf_qkv_b = (const float*)d_in[15];
  const float* tf_out_w = (const float*)d_in[16];
  const float* tf_out_b = (const float*)d_in[17];
  const float* tf_ln1_g = (const float*)d_in[18];
  const float* tf_ln1_b = (const float*)d_in[19];
  const float* tf_ff1_w = (const float*)d_in[20];
  const float* tf_ff1_b = (const float*)d_in[21];
  const float* tf_ff2_w = (const float*)d_in[22];
  const float* tf_ff2_b = (const float*)d_in[23];
  const float* tf_ln2_g = (const float*)d_in[24];
  const float* tf_ln2_b = (const float*)d_in[25];
  const float* fus_w1   = (const float*)d_in[26];
  const float* fus_b1   = (const float*)d_in[27];
  const float* fus_w2   = (const float*)d_in[28];
  const float* fus_b2   = (const float*)d_in[29];
  const float* fus_w3   = (const float*)d_in[30];
  const float* fus_b3   = (const float*)d_in[31];

  float* ws = (float*)d_ws;
  float* hard = ws;                    // NB*64 (unused, kept for layout)
  float* soft = hard + NB*64;          // NB*64 (unused)
  float* bst  = soft + NB*64;          // NB*64
  float* scores_ws = bst + NB*64;      // NB*1000
  float* partA = scores_ws + NB*LONGN; // NB*2*64
  float* partH = partA + NB*2*64;      // NB*2*64
  short* wF    = (short*)(partH + NB*2*64); // 65536 shorts (128 KB)

  hard_scores_kernel<<<2*NB, 256, 0, stream>>>(target_item_id, long_hist_ids,
      item_emb, tproj_w, tproj_b, attn_w1, attn_b1, attn_w2, attn_b2,
      hash_emb, tf_qkv_w, tf_out_w, tf_ff1_w, tf_ff2_w, wF,
      scores_ws, partA, partH);
  bst_kernel<<<NB, 512, 0, stream>>>(short_hist_ids, item_emb, wF,
      tf_qkv_b, tf_out_b, tf_ln1_g, tf_ln1_b, tf_ff1_b, tf_ff2_b,
      tf_ln2_g, tf_ln2_b, bst);
  hard_finish_fusion_kernel<<<NB, 512, 0, stream>>>(long_hist_ids, item_emb,
      sdim_w, sdim_b, scores_ws, partA, partH,
      user_features, bst, fus_w1, fus_b1, fus_w2, fus_b2, fus_w3, fus_b3,
      (float*)d_out);
}

// Round 17
// 141.532 us; speedup vs baseline: 1.3077x; 1.3077x over previous
//
#include <hip/hip_runtime.h>
#include <math.h>

#define NB 512
#define LONGN 1000
#define SHORTN 50
#define TOPKN 50
#define HALFN 500
#define NG 8          // item-groups per hard block
#define EROW 72       // hard-path bf16 LDS row stride (shorts)
#define BROW 72       // bst bf16 row stride (shorts) for xbf/obf
#define F1ROW 136     // bst bf16 row stride for ff1 output (128+8)

typedef __attribute__((ext_vector_type(8))) short bf16x8;
typedef __attribute__((ext_vector_type(4))) float f32x4;

__device__ __forceinline__ float dot4(float4 a, float4 b) {
  return a.x*b.x + a.y*b.y + a.z*b.z + a.w*b.w;
}

template<int N>
__device__ __forceinline__ float dotN(const float* w, const float* x) {
  const float4* w4 = (const float4*)w;
  const float4* x4 = (const float4*)x;
  float a0 = 0.f, a1 = 0.f, a2 = 0.f, a3 = 0.f;
  #pragma unroll
  for (int k = 0; k < N/4; k += 4) {
    a0 += dot4(w4[k],   x4[k]);
    a1 += dot4(w4[k+1], x4[k+1]);
    a2 += dot4(w4[k+2], x4[k+2]);
    a3 += dot4(w4[k+3], x4[k+3]);
  }
  return (a0 + a1) + (a2 + a3);
}

__device__ __forceinline__ float wave_sum(float v) {
  #pragma unroll
  for (int off = 32; off > 0; off >>= 1) v += __shfl_xor(v, off);
  return v;
}
__device__ __forceinline__ float wave_max(float v) {
  #pragma unroll
  for (int off = 32; off > 0; off >>= 1) v = fmaxf(v, __shfl_xor(v, off));
  return v;
}

__device__ __forceinline__ unsigned short f2bf(float x) {  // RNE fp32->bf16
  unsigned u = __float_as_uint(x);
  return (unsigned short)((u + 0x7fffu + ((u >> 16) & 1u)) >> 16);
}

// ===========================================================================
// K1 (MFMA): hard-search scores. (R15 version: (256,4), simple staged loop)
// ===========================================================================
__global__ __launch_bounds__(256, 4) void hard_scores_kernel(
    const int* __restrict__ target_item_id,
    const int* __restrict__ long_hist_ids,
    const float* __restrict__ item_emb,
    const float* __restrict__ tproj_w, const float* __restrict__ tproj_b,
    const float* __restrict__ attn_w1, const float* __restrict__ attn_b1,
    const float* __restrict__ attn_w2, const float* __restrict__ attn_b2,
    const float* __restrict__ hash_emb,
    float* __restrict__ scores_ws, float* __restrict__ partA,
    float* __restrict__ partH)
{
  __shared__ __align__(16) short Abf[64*EROW];
  __shared__ __align__(16) short Ebuf[2][64*EROW];
  __shared__ __align__(16) float tv[64];
  __shared__ __align__(16) float te[64];
  __shared__ __align__(16) float2 cw[64];
  __shared__ int idsL[HALFN];
  __shared__ __align__(16) float redE[4*64];

  const int bid = blockIdx.x;
  const int b = bid >> 1, half = bid & 1;
  const int base = half * HALFN;
  const int tid = threadIdx.x;
  const int wid = tid >> 6, lane = tid & 63;

  if (tid < 64) tv[tid] = item_emb[target_item_id[b]*64 + tid];
  for (int l = tid; l < HALFN; l += 256) idsL[l] = long_hist_ids[b*LONGN + base + l];
  __syncthreads();
  if (tid < 64) te[tid] = tproj_b[tid] + dotN<64>(tproj_w + tid*64, tv);
  __syncthreads();
  if (tid < 64) {
    float c = attn_b1[tid] + dotN<64>(attn_w1 + tid*192, te);
    cw[tid] = make_float2(c, attn_w2[tid]);
  }
  for (int idx = tid; idx < 4096; idx += 256) {
    int i = idx >> 6, j = idx & 63;
    Abf[i*EROW + j] = (short)f2bf(attn_w1[i*192 + 64 + j] + attn_w1[i*192 + 128 + j]*te[j]);
  }
  __syncthreads();

  bf16x8 a00,a01,a10,a11,a20,a21,a30,a31;
  {
    const short* ap = Abf + (lane & 15)*EROW + ((lane >> 4) << 3);
    a00 = *(const bf16x8*)(ap +  0*EROW);  a01 = *(const bf16x8*)(ap +  0*EROW + 32);
    a10 = *(const bf16x8*)(ap + 16*EROW);  a11 = *(const bf16x8*)(ap + 16*EROW + 32);
    a20 = *(const bf16x8*)(ap + 32*EROW);  a21 = *(const bf16x8*)(ap + 32*EROW + 32);
    a30 = *(const bf16x8*)(ap + 48*EROW);  a31 = *(const bf16x8*)(ap + 48*EROW + 32);
  }

  const float b2s = attn_b2[0];
  const int it_g = tid >> 2;
  const int dimg = (tid & 3) * 16;

  float4 sE0 = {0,0,0,0}, sE1 = {0,0,0,0}, sE2 = {0,0,0,0}, sE3 = {0,0,0,0};

  {
    const float4* ep = (const float4*)(item_emb + (size_t)idsL[it_g]*64 + dimg);
    float4 r0 = ep[0], r1 = ep[1], r2 = ep[2], r3 = ep[3];
    sE0.x+=r0.x; sE0.y+=r0.y; sE0.z+=r0.z; sE0.w+=r0.w;
    sE1.x+=r1.x; sE1.y+=r1.y; sE1.z+=r1.z; sE1.w+=r1.w;
    sE2.x+=r2.x; sE2.y+=r2.y; sE2.z+=r2.z; sE2.w+=r2.w;
    sE3.x+=r3.x; sE3.y+=r3.y; sE3.z+=r3.z; sE3.w+=r3.w;
    bf16x8 w0, w1;
    w0[0]=(short)f2bf(r0.x); w0[1]=(short)f2bf(r0.y); w0[2]=(short)f2bf(r0.z); w0[3]=(short)f2bf(r0.w);
    w0[4]=(short)f2bf(r1.x); w0[5]=(short)f2bf(r1.y); w0[6]=(short)f2bf(r1.z); w0[7]=(short)f2bf(r1.w);
    w1[0]=(short)f2bf(r2.x); w1[1]=(short)f2bf(r2.y); w1[2]=(short)f2bf(r2.z); w1[3]=(short)f2bf(r2.w);
    w1[4]=(short)f2bf(r3.x); w1[5]=(short)f2bf(r3.y); w1[6]=(short)f2bf(r3.z); w1[7]=(short)f2bf(r3.w);
    short* dst = &Ebuf[0][it_g*EROW + dimg];
    *(bf16x8*)dst = w0;  *(bf16x8*)(dst + 8) = w1;
  }
  __syncthreads();

  int buf = 0;
  for (int g = 0; g < NG; ++g) {
    float4 r0={0,0,0,0}, r1={0,0,0,0}, r2={0,0,0,0}, r3={0,0,0,0};
    const bool more = (g + 1 < NG);
    if (more) {
      const int gi = (g+1)*64 + it_g;
      if (gi < HALFN) {
        const float4* ep = (const float4*)(item_emb + (size_t)idsL[gi]*64 + dimg);
        r0 = ep[0]; r1 = ep[1]; r2 = ep[2]; r3 = ep[3];
      }
    }

    f32x4 acc0={0,0,0,0}, acc1={0,0,0,0}, acc2={0,0,0,0}, acc3={0,0,0,0};
    {
      const short* ep = &Ebuf[buf][(wid*16 + (lane & 15))*EROW + ((lane >> 4) << 3)];
      bf16x8 b0 = *(const bf16x8*)(ep);
      bf16x8 b1 = *(const bf16x8*)(ep + 32);
      acc0 = __builtin_amdgcn_mfma_f32_16x16x32_bf16(a00, b0, acc0, 0, 0, 0);
      acc0 = __builtin_amdgcn_mfma_f32_16x16x32_bf16(a01, b1, acc0, 0, 0, 0);
      acc1 = __builtin_amdgcn_mfma_f32_16x16x32_bf16(a10, b0, acc1, 0, 0, 0);
      acc1 = __builtin_amdgcn_mfma_f32_16x16x32_bf16(a11, b1, acc1, 0, 0, 0);
      acc2 = __builtin_amdgcn_mfma_f32_16x16x32_bf16(a20, b0, acc2, 0, 0, 0);
      acc2 = __builtin_amdgcn_mfma_f32_16x16x32_bf16(a21, b1, acc2, 0, 0, 0);
      acc3 = __builtin_amdgcn_mfma_f32_16x16x32_bf16(a30, b0, acc3, 0, 0, 0);
      acc3 = __builtin_amdgcn_mfma_f32_16x16x32_bf16(a31, b1, acc3, 0, 0, 0);
    }
    float p = 0.f;
    {
      const int rbase = (lane >> 4) << 2;
      #pragma unroll
      for (int r = 0; r < 4; ++r) {
        float2 c0 = cw[ 0 + rbase + r];
        float2 c1 = cw[16 + rbase + r];
        float2 c2 = cw[32 + rbase + r];
        float2 c3 = cw[48 + rbase + r];
        p += c0.y * fmaxf(acc0[r] + c0.x, 0.f);
        p += c1.y * fmaxf(acc1[r] + c1.x, 0.f);
        p += c2.y * fmaxf(acc2[r] + c2.x, 0.f);
        p += c3.y * fmaxf(acc3[r] + c3.x, 0.f);
      }
    }
    p += __shfl_xor(p, 16);
    p += __shfl_xor(p, 32);
    if (lane < 16) {
      const int gi = g*64 + wid*16 + lane;
      if (gi < HALFN) scores_ws[b*LONGN + base + gi] = b2s + p;
    }

    if (more) {
      sE0.x+=r0.x; sE0.y+=r0.y; sE0.z+=r0.z; sE0.w+=r0.w;
      sE1.x+=r1.x; sE1.y+=r1.y; sE1.z+=r1.z; sE1.w+=r1.w;
      sE2.x+=r2.x; sE2.y+=r2.y; sE2.z+=r2.z; sE2.w+=r2.w;
      sE3.x+=r3.x; sE3.y+=r3.y; sE3.z+=r3.z; sE3.w+=r3.w;
      bf16x8 w0, w1;
      w0[0]=(short)f2bf(r0.x); w0[1]=(short)f2bf(r0.y); w0[2]=(short)f2bf(r0.z); w0[3]=(short)f2bf(r0.w);
      w0[4]=(short)f2bf(r1.x); w0[5]=(short)f2bf(r1.y); w0[6]=(short)f2bf(r1.z); w0[7]=(short)f2bf(r1.w);
      w1[0]=(short)f2bf(r2.x); w1[1]=(short)f2bf(r2.y); w1[2]=(short)f2bf(r2.z); w1[3]=(short)f2bf(r2.w);
      w1[4]=(short)f2bf(r3.x); w1[5]=(short)f2bf(r3.y); w1[6]=(short)f2bf(r3.z); w1[7]=(short)f2bf(r3.w);
      short* dst = &Ebuf[buf ^ 1][it_g*EROW + dimg];
      *(bf16x8*)dst = w0;  *(bf16x8*)(dst + 8) = w1;
    }
    __syncthreads();
    buf ^= 1;
  }

  {
    float* red = (float*)&Ebuf[0][0];
    const int b17 = tid * 17;
    red[b17+ 0]=sE0.x; red[b17+ 1]=sE0.y; red[b17+ 2]=sE0.z; red[b17+ 3]=sE0.w;
    red[b17+ 4]=sE1.x; red[b17+ 5]=sE1.y; red[b17+ 6]=sE1.z; red[b17+ 7]=sE1.w;
    red[b17+ 8]=sE2.x; red[b17+ 9]=sE2.y; red[b17+10]=sE2.z; red[b17+11]=sE2.w;
    red[b17+12]=sE3.x; red[b17+13]=sE3.y; red[b17+14]=sE3.z; red[b17+15]=sE3.w;
    __syncthreads();
    if (tid < 64) {
      const int dg = tid >> 4, dw = tid & 15;
      float s = 0.f;
      for (int j = 0; j < 64; ++j) s += red[(j*4 + dg)*17 + dw];
      partA[bid*64 + tid] = s;
    }
  }

  {
    const int hl = lane >> 4, dd = lane & 15;
    const float* hb = hash_emb + hl*1024*16 + dd;
    float accH = 0.f;
    for (int l = wid; l < HALFN; l += 4)
      accH += hb[(idsL[l] & 1023)*16];
    redE[wid*64 + lane] = accH;
  }
  __syncthreads();
  if (wid == 0)
    partH[bid*64 + lane] = redE[lane] + redE[64+lane] + redE[128+lane] + redE[192+lane];
}

// ===========================================================================
// BST weight prep (separate launch, as in R15).
// ===========================================================================
__global__ __launch_bounds__(256) void bst_prep_kernel(
    const float* __restrict__ qkv_w, const float* __restrict__ out_w,
    const float* __restrict__ ff1_w, const float* __restrict__ ff2_w,
    short* __restrict__ wF)
{
  const int t = blockIdx.x*256 + threadIdx.x;   // 8192 threads
  if (t >= 8192) return;
  const int fid = t >> 6, lane = t & 63;
  const int n16 = lane & 15, k8 = (lane >> 4) * 8;
  const float* src;
  if (fid < 48)      { int f=fid,    l=f/24, r=f%24, nt=r>>1, kc=r&1;
    src = qkv_w + l*12288 + (nt*16+n16)*64 + kc*32 + k8; }
  else if (fid < 64) { int f=fid-48, l=f>>3, r=f&7,  nt=r>>1, kc=r&1;
    src = out_w + l*4096 + (nt*16+n16)*64 + kc*32 + k8; }
  else if (fid < 96) { int f=fid-64, l=f>>4, r=f&15, nt=r>>1, kc=r&1;
    src = ff1_w + l*8192 + (nt*16+n16)*64 + kc*32 + k8; }
  else               { int f=fid-96, l=f>>4, r=f&15, nt=r>>2, kc=r&3;
    src = ff2_w + l*8192 + (nt*16+n16)*128 + kc*32 + k8; }
  short* dst = wF + fid*512 + lane*8;
  #pragma unroll
  for (int j = 0; j < 8; ++j) dst[j] = (short)f2bf(src[j]);
}

// ===========================================================================
// BST transformer v10 (R15): 512 threads, M-split waves, 400-thread K-split
// attention.
// ===========================================================================
__global__ __launch_bounds__(512, 2) void bst_kernel(
    const int* __restrict__ short_ids, const float* __restrict__ item_emb,
    const short* __restrict__ wF,
    const float* __restrict__ qkv_b, const float* __restrict__ out_b,
    const float* __restrict__ ln1_g, const float* __restrict__ ln1_b,
    const float* __restrict__ ff1_b, const float* __restrict__ ff2_b,
    const float* __restrict__ ln2_g, const float* __restrict__ ln2_b,
    float* __restrict__ bst_out)
{
  __shared__ __align__(16) float xf[SHORTN*64];
  __shared__ __align__(16) short xbf[64*BROW];
  __shared__ __align__(16) float qf[SHORTN*68];
  __shared__ __align__(16) float arena[SHORTN*132];
  __shared__ __align__(16) short obf[64*BROW];

  short* f1bf = (short*)arena;

  const int b = blockIdx.x, tid = threadIdx.x;
  const int w8 = tid >> 6, lane = tid & 63;
  const int mh = w8 & 1, wg = w8 >> 1;
  const int n16 = lane & 15;
  const int kg8 = (lane >> 4) << 3;
  const int mrow = (lane >> 4) << 2;
  const int rb = 32*mh;

  for (int idx = tid; idx < SHORTN*64; idx += 512) {
    int s = idx >> 6, j = idx & 63;
    float v = item_emb[short_ids[b*SHORTN + s]*64 + j];
    xf[idx] = v;
    xbf[s*BROW + j] = (short)f2bf(v);
  }
  for (int idx = tid; idx < 14*BROW; idx += 512) {
    xbf[50*BROW + idx] = 0;
    obf[50*BROW + idx] = 0;
  }
  __syncthreads();

  for (int l = 0; l < 2; ++l) {
    // ======== qkv ========
    {
      const short* ap = xbf + (rb + n16)*BROW + kg8;
      bf16x8 A00 = *(const bf16x8*)(ap);            bf16x8 A01 = *(const bf16x8*)(ap + 32);
      bf16x8 A10 = *(const bf16x8*)(ap + 16*BROW);  bf16x8 A11 = *(const bf16x8*)(ap + 16*BROW + 32);
      #pragma unroll
      for (int t = 0; t < 3; ++t) {
        const int nt = wg*3 + t;
        const short* bp = wF + (size_t)(l*24 + nt*2)*512 + lane*8;
        bf16x8 B0 = *(const bf16x8*)(bp);
        bf16x8 B1 = *(const bf16x8*)(bp + 512);
        f32x4 c0={0,0,0,0}, c1={0,0,0,0};
        c0 = __builtin_amdgcn_mfma_f32_16x16x32_bf16(A00, B0, c0, 0,0,0);
        c0 = __builtin_amdgcn_mfma_f32_16x16x32_bf16(A01, B1, c0, 0,0,0);
        c1 = __builtin_amdgcn_mfma_f32_16x16x32_bf16(A10, B0, c1, 0,0,0);
        c1 = __builtin_amdgcn_mfma_f32_16x16x32_bf16(A11, B1, c1, 0,0,0);
        const int c = nt*16 + n16;
        const float bias = qkv_b[l*192 + c];
        #pragma unroll
        for (int r = 0; r < 4; ++r) {
          const int r0 = rb + mrow + r;
          const int r1 = r0 + 16;
          float v0 = c0[r] + bias;
          float v1 = c1[r] + bias;
          if (c < 64) {
            qf[r0*68 + c] = v0;
            if (r1 < SHORTN) qf[r1*68 + c] = v1;
          } else {
            const int cc = c - 64;
            arena[r0*132 + cc] = v0;
            if (r1 < SHORTN) arena[r1*132 + cc] = v1;
          }
        }
      }
    }
    __syncthreads();

    // ======== attention: 400 threads, pair-split K ========
    if (tid < 8*SHORTN) {
      const int pair = tid >> 1, khalf = tid & 1;
      const int h = pair / SHORTN, s = pair - h*SHORTN;
      const float4* qp = (const float4*)(qf + s*68 + h*16);
      const float4 qA = qp[0], qB2 = qp[1], qC = qp[2], qD = qp[3];
      float ss = 0.f;
      float4 oa0 = {0,0,0,0}, oa1 = {0,0,0,0}, oa2 = {0,0,0,0}, oa3 = {0,0,0,0};
      const int t0 = khalf*25;
      for (int t2 = t0; t2 < t0 + 25; ++t2) {
        const float4* kp = (const float4*)(arena + t2*132 + h*16);
        float d = dot4(qA,kp[0]) + dot4(qB2,kp[1]) + dot4(qC,kp[2]) + dot4(qD,kp[3]);
        float p = __expf(d*0.25f);
        ss += p;
        const float4* vp = (const float4*)(arena + t2*132 + 64 + h*16);
        float4 v0 = vp[0], v1 = vp[1], v2 = vp[2], v3 = vp[3];
        oa0.x += p*v0.x; oa0.y += p*v0.y; oa0.z += p*v0.z; oa0.w += p*v0.w;
        oa1.x += p*v1.x; oa1.y += p*v1.y; oa1.z += p*v1.z; oa1.w += p*v1.w;
        oa2.x += p*v2.x; oa2.y += p*v2.y; oa2.z += p*v2.z; oa2.w += p*v2.w;
        oa3.x += p*v3.x; oa3.y += p*v3.y; oa3.z += p*v3.z; oa3.w += p*v3.w;
      }
      ss    += __shfl_xor(ss, 1);
      oa0.x += __shfl_xor(oa0.x, 1); oa0.y += __shfl_xor(oa0.y, 1);
      oa0.z += __shfl_xor(oa0.z, 1); oa0.w += __shfl_xor(oa0.w, 1);
      oa1.x += __shfl_xor(oa1.x, 1); oa1.y += __shfl_xor(oa1.y, 1);
      oa1.z += __shfl_xor(oa1.z, 1); oa1.w += __shfl_xor(oa1.w, 1);
      oa2.x += __shfl_xor(oa2.x, 1); oa2.y += __shfl_xor(oa2.y, 1);
      oa2.z += __shfl_xor(oa2.z, 1); oa2.w += __shfl_xor(oa2.w, 1);
      oa3.x += __shfl_xor(oa3.x, 1); oa3.y += __shfl_xor(oa3.y, 1);
      oa3.z += __shfl_xor(oa3.z, 1); oa3.w += __shfl_xor(oa3.w, 1);
      if (khalf == 0) {
        const float inv = 1.f/ss;
        bf16x8 w0, w1;
        w0[0]=(short)f2bf(oa0.x*inv); w0[1]=(short)f2bf(oa0.y*inv);
        w0[2]=(short)f2bf(oa0.z*inv); w0[3]=(short)f2bf(oa0.w*inv);
        w0[4]=(short)f2bf(oa1.x*inv); w0[5]=(short)f2bf(oa1.y*inv);
        w0[6]=(short)f2bf(oa1.z*inv); w0[7]=(short)f2bf(oa1.w*inv);
        w1[0]=(short)f2bf(oa2.x*inv); w1[1]=(short)f2bf(oa2.y*inv);
        w1[2]=(short)f2bf(oa2.z*inv); w1[3]=(short)f2bf(oa2.w*inv);
        w1[4]=(short)f2bf(oa3.x*inv); w1[5]=(short)f2bf(oa3.y*inv);
        w1[6]=(short)f2bf(oa3.z*inv); w1[7]=(short)f2bf(oa3.w*inv);
        short* op = obf + s*BROW + h*16;
        *(bf16x8*)op = w0;  *(bf16x8*)(op + 8) = w1;
      }
    }
    __syncthreads();

    // ======== out-proj + y ========
    {
      const short* ap = obf + (rb + n16)*BROW + kg8;
      bf16x8 A00 = *(const bf16x8*)(ap);            bf16x8 A01 = *(const bf16x8*)(ap + 32);
      bf16x8 A10 = *(const bf16x8*)(ap + 16*BROW);  bf16x8 A11 = *(const bf16x8*)(ap + 16*BROW + 32);
      const int nt = wg;
      const short* bp = wF + (size_t)(48 + l*8 + nt*2)*512 + lane*8;
      bf16x8 B0 = *(const bf16x8*)(bp);
      bf16x8 B1 = *(const bf16x8*)(bp + 512);
      f32x4 c0={0,0,0,0}, c1={0,0,0,0};
      c0 = __builtin_amdgcn_mfma_f32_16x16x32_bf16(A00, B0, c0, 0,0,0);
      c0 = __builtin_amdgcn_mfma_f32_16x16x32_bf16(A01, B1, c0, 0,0,0);
      c1 = __builtin_amdgcn_mfma_f32_16x16x32_bf16(A10, B0, c1, 0,0,0);
      c1 = __builtin_amdgcn_mfma_f32_16x16x32_bf16(A11, B1, c1, 0,0,0);
      const int c = nt*16 + n16;
      const float bias = out_b[l*64 + c];
      #pragma unroll
      for (int r = 0; r < 4; ++r) {
        const int r0 = rb + mrow + r;
        const int r1 = r0 + 16;
        arena[r0*68 + c] = xf[r0*64 + c] + bias + c0[r];
        if (r1 < SHORTN) arena[r1*68 + c] = xf[r1*64 + c] + bias + c1[r];
      }
      for (int idx = tid; idx < 14*F1ROW; idx += 512) f1bf[50*F1ROW + idx] = 0;
    }
    __syncthreads();

    // ======== LN1 ========
    {
      const float g = ln1_g[l*64 + lane], bb = ln1_b[l*64 + lane];
      for (int s = w8; s < SHORTN; s += 8) {
        float y = arena[s*68 + lane];
        float mean = wave_sum(y) * (1.f/64.f);
        float dv = y - mean;
        float var = wave_sum(dv*dv) * (1.f/64.f);
        float r = dv / sqrtf(var + 1e-5f) * g + bb;
        xf[s*64 + lane] = r;
        xbf[s*BROW + lane] = (short)f2bf(r);
      }
    }
    __syncthreads();

    // ======== ff1 ========
    {
      const short* ap = xbf + (rb + n16)*BROW + kg8;
      bf16x8 A00 = *(const bf16x8*)(ap);            bf16x8 A01 = *(const bf16x8*)(ap + 32);
      bf16x8 A10 = *(const bf16x8*)(ap + 16*BROW);  bf16x8 A11 = *(const bf16x8*)(ap + 16*BROW + 32);
      #pragma unroll
      for (int t = 0; t < 2; ++t) {
        const int nt = wg*2 + t;
        const short* bp = wF + (size_t)(64 + l*16 + nt*2)*512 + lane*8;
        bf16x8 B0 = *(const bf16x8*)(bp);
        bf16x8 B1 = *(const bf16x8*)(bp + 512);
        f32x4 c0={0,0,0,0}, c1={0,0,0,0};
        c0 = __builtin_amdgcn_mfma_f32_16x16x32_bf16(A00, B0, c0, 0,0,0);
        c0 = __builtin_amdgcn_mfma_f32_16x16x32_bf16(A01, B1, c0, 0,0,0);
        c1 = __builtin_amdgcn_mfma_f32_16x16x32_bf16(A10, B0, c1, 0,0,0);
        c1 = __builtin_amdgcn_mfma_f32_16x16x32_bf16(A11, B1, c1, 0,0,0);
        const int c = nt*16 + n16;
        const float bias = ff1_b[l*128 + c];
        #pragma unroll
        for (int r = 0; r < 4; ++r) {
          const int r0 = rb + mrow + r;
          const int r1 = r0 + 16;
          f1bf[r0*F1ROW + c] = (short)f2bf(fmaxf(c0[r] + bias, 0.f));
          if (r1 < SHORTN) f1bf[r1*F1ROW + c] = (short)f2bf(fmaxf(c1[r] + bias, 0.f));
        }
      }
    }
    __syncthreads();

    // ======== ff2 ========
    {
      const int nt = wg;
      f32x4 c0={0,0,0,0}, c1={0,0,0,0};
      #pragma unroll
      for (int kc = 0; kc < 4; ++kc) {
        const short* ap = f1bf + (rb + n16)*F1ROW + kc*32 + kg8;
        bf16x8 A0 = *(const bf16x8*)(ap);
        bf16x8 A1 = *(const bf16x8*)(ap + 16*F1ROW);
        const short* bp = wF + (size_t)(96 + l*16 + nt*4 + kc)*512 + lane*8;
        bf16x8 B = *(const bf16x8*)(bp);
        c0 = __builtin_amdgcn_mfma_f32_16x16x32_bf16(A0, B, c0, 0,0,0);
        c1 = __builtin_amdgcn_mfma_f32_16x16x32_bf16(A1, B, c1, 0,0,0);
      }
      __syncthreads();
      const int c = nt*16 + n16;
      const float bias = ff2_b[l*64 + c];
      #pragma unroll
      for (int r = 0; r < 4; ++r) {
        const int r0 = rb + mrow + r;
        const int r1 = r0 + 16;
        arena[r0*68 + c] = xf[r0*64 + c] + bias + c0[r];
        if (r1 < SHORTN) arena[r1*68 + c] = xf[r1*64 + c] + bias + c1[r];
      }
    }
    __syncthreads();

    // ======== LN2 ========
    {
      const float g = ln2_g[l*64 + lane], bb = ln2_b[l*64 + lane];
      for (int s = w8; s < SHORTN; s += 8) {
        float y = arena[s*68 + lane];
        float mean = wave_sum(y) * (1.f/64.f);
        float dv = y - mean;
        float var = wave_sum(dv*dv) * (1.f/64.f);
        float r = dv / sqrtf(var + 1e-5f) * g + bb;
        xf[s*64 + lane] = r;
        xbf[s*BROW + lane] = (short)f2bf(r);
      }
    }
    __syncthreads();
  }

  float acc = 0.f;
  for (int s = w8; s < SHORTN; s += 8) acc += xf[s*64 + lane];
  qf[w8*64 + lane] = acc;
  __syncthreads();
  if (w8 == 0) {
    float t = qf[lane];
    #pragma unroll
    for (int w = 1; w < 8; ++w) t += qf[w*64 + lane];
    bst_out[b*64 + lane] = t * (1.f/50.f);
  }
}

// ===========================================================================
// K2+K4 merged, 512 threads (R15).
// ===========================================================================
__global__ __launch_bounds__(512) void hard_finish_fusion_kernel(
    const int* __restrict__ long_hist_ids,
    const float* __restrict__ item_emb,
    const float* __restrict__ sdim_w, const float* __restrict__ sdim_b,
    const float* __restrict__ scores_ws,
    const float* __restrict__ partA, const float* __restrict__ partH,
    const float* __restrict__ user, const float* __restrict__ bst,
    const float* __restrict__ w1, const float* __restrict__ b1,
    const float* __restrict__ w2, const float* __restrict__ b2,
    const float* __restrict__ w3, const float* __restrict__ b3,
    float* __restrict__ out)
{
  __shared__ __align__(16) float scores[LONGN];
  __shared__ int   idsL[LONGN];
  __shared__ __align__(16) unsigned long long kv[1024];
  __shared__ __align__(16) float redE[8*64];
  __shared__ __align__(16) float vecbuf[64];
  __shared__ float redV[8];
  __shared__ float selV[TOPKN];
  __shared__ int   selI[TOPKN];
  __shared__ __align__(16) float comb[256];
  __shared__ __align__(16) float h1[256];
  __shared__ __align__(16) float h2[128];

  const int b = blockIdx.x;
  const int tid = threadIdx.x;
  const int wid = tid >> 6, lane = tid & 63;

  for (int l = tid; l < LONGN; l += 512) {
    scores[l] = scores_ws[b*LONGN + l];
    idsL[l] = long_hist_ids[b*LONGN + l];
  }
  if (tid < 64)                          comb[tid] = user[b*64 + tid];
  else if (tid >= 192 && tid < 256)      comb[tid] = bst[b*64 + tid - 192];
  __syncthreads();

  if (tid < 64)
    vecbuf[tid] = (partA[(2*b)*64 + tid] + partA[(2*b+1)*64 + tid]
                 + partH[(2*b)*64 + tid] + partH[(2*b+1)*64 + tid]) * (1.f/1000.f);
  __syncthreads();
  if (tid < 64)
    comb[128 + tid] = sdim_b[tid] + dotN<64>(sdim_w + tid*64, vecbuf);

  float mx = -INFINITY;
  for (int l = tid; l < LONGN; l += 512) mx = fmaxf(mx, scores[l]);
  mx = wave_max(mx);
  if (lane == 0) redV[wid] = mx;
  __syncthreads();
  mx = redV[0];
  #pragma unroll
  for (int w = 1; w < 8; ++w) mx = fmaxf(mx, redV[w]);
  __syncthreads();
  float sm = 0.f;
  for (int l = tid; l < LONGN; l += 512) {
    float a = expf(scores[l] - mx);
    scores[l] = a;
    sm += a;
  }
  sm = wave_sum(sm);
  if (lane == 0) redV[wid] = sm;
  __syncthreads();
  {
    float tot = redV[0];
    #pragma unroll
    for (int w = 1; w < 8; ++w) tot += redV[w];
    const float inv = 1.f / tot;
    for (int l = tid; l < LONGN; l += 512) scores[l] *= inv;
  }
  __syncthreads();

  for (int l = tid; l < 1024; l += 512) {
    if (l < LONGN) {
      unsigned vb = __float_as_uint(scores[l]);
      kv[l] = ((unsigned long long)(~vb) << 32) | (unsigned)l;
    } else {
      kv[l] = 0xFFFFFFFFFFFFFFFFull;
    }
  }
  __syncthreads();

  for (int k = 2; k <= 1024; k <<= 1) {
    for (int j = k >> 1; j > 0; j >>= 1) {
      {
        const int p = tid;
        const int i = ((p & ~(j-1)) << 1) | (p & (j-1));
        const int m = i + j;
        const bool up = ((i & k) == 0);
        unsigned long long a = kv[i], c = kv[m];
        if ((a > c) == up) { kv[i] = c; kv[m] = a; }
      }
      __syncthreads();
    }
  }

  if (tid < TOPKN) {
    unsigned long long key = kv[tid];
    selI[tid] = (int)(unsigned)(key & 0xFFFFFFFFu);
    selV[tid] = __uint_as_float(~(unsigned)(key >> 32));
  }
  __syncthreads();

  if (wid == 0) {
    float v = (lane < TOPKN) ? selV[lane] : -INFINITY;
    float m2 = wave_max(v);
    float e = (lane < TOPKN) ? expf(v - m2) : 0.f;
    float s2 = wave_sum(e);
    if (lane < TOPKN) selV[lane] = e / s2;
  }
  __syncthreads();

  float accR = 0.f;
  for (int r = wid; r < TOPKN; r += 8)
    accR += selV[r] * item_emb[idsL[selI[r]]*64 + lane];
  redE[wid*64 + lane] = accR;
  __syncthreads();
  if (wid == 0) {
    float t = redE[lane];
    #pragma unroll
    for (int w = 1; w < 8; ++w) t += redE[w*64 + lane];
    comb[64 + lane] = t;
  }
  __syncthreads();

  if (tid < 256) h1[tid] = fmaxf(b1[tid] + dotN<256>(w1 + tid*256, comb), 0.f);
  __syncthreads();
  if (tid < 128) h2[tid] = fmaxf(b2[tid] + dotN<256>(w2 + tid*256, h1), 0.f);
  __syncthreads();
  if (tid < 64) {
    float p = w3[tid]*h2[tid] + w3[tid+64]*h2[tid+64];
    p = wave_sum(p);
    if (tid == 0) out[b] = p + b3[0];
  }
}

extern "C" void kernel_launch(void* const* d_in, const int* in_sizes, int n_in,
                              void* d_out, int out_size, void* d_ws, size_t ws_size,
                              hipStream_t stream) {
  const float* user_features  = (const float*)d_in[0];
  const int*   target_item_id = (const int*)  d_in[1];
  const int*   short_hist_ids = (const int*)  d_in[2];
  const int*   long_hist_ids  = (const int*)  d_in[3];
  const float* item_emb       = (const float*)d_in[4];
  const float* tproj_w  = (const float*)d_in[5];
  const float* tproj_b  = (const float*)d_in[6];
  const float* attn_w1  = (const float*)d_in[7];
  const float* attn_b1  = (const float*)d_in[8];
  const float* attn_w2  = (const float*)d_in[9];
  const float* attn_b2  = (const float*)d_in[10];
  const float* hash_emb = (const float*)d_in[11];
  const float* sdim_w   = (const float*)d_in[12];
  const float* sdim_b   = (const float*)d_in[13];
  const float* tf_qkv_w = (const float*)d_in[14];
  const float* tf_qkv_b = (const float*)d_in[15];
  const float* tf_out_w = (const float*)d_in[16];
  const float* tf_out_b = (const float*)d_in[17];
  const float* tf_ln1_g = (const float*)d_in[18];
  const float* tf_ln1_b = (const float*)d_in[19];
  const float* tf_ff1_w = (const float*)d_in[20];
  const float* tf_ff1_b = (const float*)d_in[21];
  const float* tf_ff2_w = (const float*)d_in[22];
  const float* tf_ff2_b = (const float*)d_in[23];
  const float* tf_ln2_g = (const float*)d_in[24];
  const float* tf_ln2_b = (const float*)d_in[25];
  const float* fus_w1   = (const float*)d_in[26];
  const float* fus_b1   = (const float*)d_in[27];
  const float* fus_w2   = (const float*)d_in[28];
  const float* fus_b2   = (const float*)d_in[29];
  const float* fus_w3   = (const float*)d_in[30];
  const float* fus_b3   = (const float*)d_in[31];

  float* ws = (float*)d_ws;
  float* hard = ws;                    // NB*64 (unused, kept for layout)
  float* soft = hard + NB*64;          // NB*64 (unused)
  float* bst  = soft + NB*64;          // NB*64
  float* scores_ws = bst + NB*64;      // NB*1000
  float* partA = scores_ws + NB*LONGN; // NB*2*64
  float* partH = partA + NB*2*64;      // NB*2*64
  short* wF    = (short*)(partH + NB*2*64); // 65536 shorts (128 KB)

  bst_prep_kernel<<<32, 256, 0, stream>>>(tf_qkv_w, tf_out_w, tf_ff1_w, tf_ff2_w, wF);
  hard_scores_kernel<<<2*NB, 256, 0, stream>>>(target_item_id, long_hist_ids,
      item_emb, tproj_w, tproj_b, attn_w1, attn_b1, attn_w2, attn_b2,
      hash_emb, scores_ws, partA, partH);
  bst_kernel<<<NB, 512, 0, stream>>>(short_hist_ids, item_emb, wF,
      tf_qkv_b, tf_out_b, tf_ln1_g, tf_ln1_b, tf_ff1_b, tf_ff2_b,
      tf_ln2_g, tf_ln2_b, bst);
  hard_finish_fusion_kernel<<<NB, 512, 0, stream>>>(long_hist_ids, item_emb,
      sdim_w, sdim_b, scores_ws, partA, partH,
      user_features, bst, fus_w1, fus_b1, fus_w2, fus_b2, fus_w3, fus_b3,
      (float*)d_out);
}